// Round 3
// baseline (204.397 us; speedup 1.0000x reference)
//
#include <hip/hip_runtime.h>

#define N_SAMPLES 4096
#define DIM 2048
#define NUM_CLASSES 128
#define MARGIN 0.5f

// ---------------- ws layout (byte offsets) ----------------
// cnt   : C ints                      @ 0
// meanR : C*D floats                  @ 1024
// meanT : C*D floats                  @ 1024 + C*D*4
// stats : 4*C floats (rn,tn,cn,sqd)   @ 1024 + 2*C*D*4
//
// History:
//   R3  = 118.8 us (4-deep unroll mean, 256-block loss).
//   R5  (nontemporal + 8-deep unroll): +13 us — regression.
//   R6  (loss algebraic refactor): +7 us — reverted.
//   R8  = 115.4 us: loss 4-waves/tile. Win (-4.3).
//   R9  = 115.6 us: copy-free ping-pong mean — NEUTRAL (compiler had
//         already pipelined R8's version; mean is at ~BW floor).
//   R10 (this): replace the O(C^2 * D) pairwise loss (128 MB of mean
//        re-reads) with exact norm-bound pruning:
//          off-diag margin term nonzero iff sq < 0.5^4 = 0.0625, and
//          sq >= (|ra|-|cb|)^2  (reverse triangle ineq). One FMA per
//          pair decides it; full-D fallback loop keeps exactness for
//          adversarial inputs. Diag term = 2*max(0.25*|r-t|^2, 1e-12).
//        -> stat_kernel (2 MB) + pair_kernel (KBs) replace loss_kernel.

// Kernel 1: per-class means, self-contained (no pre-sort).
// grid (2, C, 2), block 256. Each block scans targets (16 KB, L2-hot),
// compacts its class's rows into LDS, then streams its rows' float4
// columns with a copy-free ping-pong pipeline. Inputs read exactly once.
__global__ __launch_bounds__(256) void mean_kernel(
        const float* __restrict__ x1,
        const float* __restrict__ x2,
        const int* __restrict__ targets,
        int* __restrict__ cnt,
        float* __restrict__ meanR,
        float* __restrict__ meanT,
        float* __restrict__ d_out, int out_size) {
    __shared__ int s_rows[N_SAMPLES];
    __shared__ int s_n;
    const int tid = threadIdx.x;
    const int c = blockIdx.y;
    const float* __restrict__ x = (blockIdx.z == 0) ? x1 : x2;
    float* __restrict__ mean    = (blockIdx.z == 0) ? meanR : meanT;

    if (tid == 0) s_n = 0;
    if (blockIdx.x == 0 && blockIdx.y == 0 && blockIdx.z == 0) {
        for (int i = tid; i < out_size; i += 256) d_out[i] = 0.0f;  // pair runs after us
    }
    __syncthreads();

    // compact rows of class c (order irrelevant)
    const int4* __restrict__ t4 = (const int4*)targets;
    for (int i = tid; i < N_SAMPLES / 4; i += 256) {
        const int4 v = t4[i];
        const int base = i * 4;
        if (v.x == c) s_rows[atomicAdd(&s_n, 1)] = base;
        if (v.y == c) s_rows[atomicAdd(&s_n, 1)] = base + 1;
        if (v.z == c) s_rows[atomicAdd(&s_n, 1)] = base + 2;
        if (v.w == c) s_rows[atomicAdd(&s_n, 1)] = base + 3;
    }
    __syncthreads();
    const int n = s_n;

    const int col = blockIdx.x * 256 + tid;          // float4 index in [0,512)
    const float4* __restrict__ xs = (const float4*)x;
    float ax = 0.0f, ay = 0.0f, az = 0.0f, aw = 0.0f;

#define LOADG(B, g) do {                                               \
        const int _base = (g) * 8;                                     \
        _Pragma("unroll")                                              \
        for (int u = 0; u < 8; ++u) {                                  \
            const int _r = s_rows[_base + u];                          \
            B[u] = xs[(size_t)_r * (DIM / 4) + col];                   \
        }                                                              \
    } while (0)

#define ACCG(B) do {                                                   \
        _Pragma("unroll")                                              \
        for (int u = 0; u < 8; ++u) {                                  \
            ax += B[u].x; ay += B[u].y; az += B[u].z; aw += B[u].w;    \
        }                                                              \
    } while (0)

    const int nfull = n >> 3;        // full 8-row groups
    const int rem   = n & 7;         // 0..7 tail rows

    // Tail group: clamped indices, loads issued FIRST so their latency
    // hides under the whole body; masked accumulate at the very end.
    float4 T[8];
    if (rem) {
        const int tbase = nfull * 8;
#pragma unroll
        for (int u = 0; u < 8; ++u) {
            const int idx = tbase + ((u < rem) ? u : 0);  // clamp (uniform)
            T[u] = xs[(size_t)s_rows[idx] * (DIM / 4) + col];
        }
    }

    // Copy-free ping-pong body: acc(X) waits vmcnt(8) while the other
    // group's 8 loads remain in flight.
    if (nfull > 0) {
        float4 bufA[8], bufB[8];
        LOADG(bufA, 0);
        int g = 1;
        for (; g + 1 < nfull; g += 2) {
            LOADG(bufB, g);
            ACCG(bufA);
            LOADG(bufA, g + 1);
            ACCG(bufB);
        }
        if (g < nfull) {             // one loaded group + one pending
            LOADG(bufB, g);
            ACCG(bufA);
            ACCG(bufB);
        } else {
            ACCG(bufA);
        }
    }

    if (rem) {
#pragma unroll
        for (int u = 0; u < 8; ++u) {
            const float m = (u < rem) ? 1.0f : 0.0f;
            ax = fmaf(T[u].x, m, ax);
            ay = fmaf(T[u].y, m, ay);
            az = fmaf(T[u].z, m, az);
            aw = fmaf(T[u].w, m, aw);
        }
    }
#undef LOADG
#undef ACCG

    const float inv = 1.0f / (float)((n > 0) ? n : 1);
    float4 m; m.x = ax * inv; m.y = ay * inv; m.z = az * inv; m.w = aw * inv;
    ((float4*)mean)[(size_t)c * (DIM / 4) + col] = m;

    if (blockIdx.x == 0 && blockIdx.z == 0 && tid == 0) cnt[c] = n;
}

__device__ __forceinline__ float wave_sum64(float v) {
#pragma unroll
    for (int m = 32; m >= 1; m >>= 1) v += __shfl_xor(v, m, 64);
    return v;
}

// Kernel 2: per-class stats. One block per class (128 blocks).
// stats[0][c] = |meanR[c]|            (rn)
// stats[1][c] = |meanT[c]|            (tn)
// stats[2][c] = |0.5(R+T)[c]|         (cn)
// stats[3][c] = 0.25*|R[c]-T[c]|^2    (sqd — the shared diagonal sq-dist)
__global__ __launch_bounds__(256) void stat_kernel(
        const float* __restrict__ meanR,
        const float* __restrict__ meanT,
        float* __restrict__ stats) {
    const int c = blockIdx.x;
    const int tid = threadIdx.x;
    const float4* __restrict__ r4 = (const float4*)(meanR + (size_t)c * DIM);
    const float4* __restrict__ t4 = (const float4*)(meanT + (size_t)c * DIM);
    float sr = 0.0f, st = 0.0f, sc = 0.0f, sd = 0.0f;
    for (int i = tid; i < DIM / 4; i += 256) {   // 2 iterations
        const float4 r = r4[i], t = t4[i];
        float cx, dx;
#define DO(f) cx = 0.5f * (r.f + t.f); dx = r.f - t.f;               \
        sr = fmaf(r.f, r.f, sr); st = fmaf(t.f, t.f, st);            \
        sc = fmaf(cx, cx, sc);   sd = fmaf(dx, dx, sd);
        DO(x) DO(y) DO(z) DO(w)
#undef DO
    }
    sr = wave_sum64(sr); st = wave_sum64(st);
    sc = wave_sum64(sc); sd = wave_sum64(sd);
    __shared__ float s[4][4];
    const int wave = tid >> 6;
    if ((tid & 63) == 0) {
        s[wave][0] = sr; s[wave][1] = st; s[wave][2] = sc; s[wave][3] = sd;
    }
    __syncthreads();
    if (tid < 4) {
        float v = (s[0][tid] + s[1][tid]) + (s[2][tid] + s[3][tid]);
        v = (tid < 3) ? sqrtf(v) : 0.25f * v;
        stats[tid * NUM_CLASSES + c] = v;
    }
}

// Kernel 3: pair loss. 16384 pairs -> 64 blocks x 256 threads, one pair
// per thread. Off-diag margin term is nonzero iff sq < MARGIN^4; prune
// with sq >= (|a|-|c_b|)^2. Fallback: exact full-D distance (rare/never).
__global__ __launch_bounds__(256) void pair_kernel(
        const float* __restrict__ meanR,
        const float* __restrict__ meanT,
        const float* __restrict__ stats,
        const int* __restrict__ cnt,
        float* __restrict__ d_out) {
    const int idx = blockIdx.x * 256 + threadIdx.x;   // 0..16383
    const int a = idx >> 7;          // wave-uniform (scalar loads)
    const int b = idx & 127;         // coalesced
    const float* __restrict__ rn  = stats;
    const float* __restrict__ tn  = stats + NUM_CLASSES;
    const float* __restrict__ cn  = stats + 2 * NUM_CLASSES;
    const float* __restrict__ sqd = stats + 3 * NUM_CLASSES;

    const float invN2 = 1.0f / ((float)N_SAMPLES * (float)N_SAMPLES);
    const float w = (float)cnt[a] * (float)cnt[b] * invN2;

    float total;
    if (a == b) {
        const float t = fmaxf(sqd[a], 1e-12f);   // d^2 for BOTH modalities
        total = w * (t + t);
    } else {
        const float THR = MARGIN * MARGIN * MARGIN * MARGIN;  // 0.0625
        const float g1 = rn[a] - cn[b];
        const float g2 = tn[a] - cn[b];
        float t1 = 0.0f, t2 = 0.0f;
        if ((g1 * g1 < THR) | (g2 * g2 < THR)) {
            // exact squared distances (correctness fallback; never taken
            // on data where class means are well separated)
            float sq1 = 0.0f, sq2 = 0.0f;
            const float* __restrict__ ra = meanR + (size_t)a * DIM;
            const float* __restrict__ ta = meanT + (size_t)a * DIM;
            const float* __restrict__ rb = meanR + (size_t)b * DIM;
            const float* __restrict__ tb = meanT + (size_t)b * DIM;
            for (int k = 0; k < DIM; ++k) {
                const float cb = 0.5f * (rb[k] + tb[k]);
                const float e1 = ra[k] - cb;
                const float e2 = ta[k] - cb;
                sq1 = fmaf(e1, e1, sq1);
                sq2 = fmaf(e2, e2, sq2);
            }
            sq1 = fmaxf(sq1, 1e-12f);
            sq2 = fmaxf(sq2, 1e-12f);
            const float dd1 = sqrtf(sqrtf(sq1) + 1e-10f);
            const float dd2 = sqrtf(sqrtf(sq2) + 1e-10f);
            const float r1 = fmaxf(MARGIN - dd1, 0.0f);
            const float r2 = fmaxf(MARGIN - dd2, 0.0f);
            t1 = r1 * r1;
            t2 = r2 * r2;
        }
        total = w * (t1 + t2);
    }

    total = wave_sum64(total);
    __shared__ float sp[4];
    if ((threadIdx.x & 63) == 0) sp[threadIdx.x >> 6] = total;
    __syncthreads();
    if (threadIdx.x == 0)
        atomicAdd(d_out, (sp[0] + sp[1]) + (sp[2] + sp[3]));
}

extern "C" void kernel_launch(void* const* d_in, const int* in_sizes, int n_in,
                              void* d_out, int out_size, void* d_ws, size_t ws_size,
                              hipStream_t stream) {
    const float* modal1 = (const float*)d_in[0];
    const float* modal2 = (const float*)d_in[1];
    const int* targets  = (const int*)d_in[2];
    float* out = (float*)d_out;

    char* ws = (char*)d_ws;
    int*   cnt   = (int*)(ws + 0);
    float* meanR = (float*)(ws + 1024);
    float* meanT = (float*)(ws + 1024 + (size_t)NUM_CLASSES * DIM * 4);
    float* stats = (float*)(ws + 1024 + 2 * (size_t)NUM_CLASSES * DIM * 4);

    // 1. per-class means (self-gathering; also zeroes d_out, publishes cnt)
    dim3 gridB(2, NUM_CLASSES, 2);
    mean_kernel<<<gridB, 256, 0, stream>>>(modal1, modal2, targets, cnt,
                                           meanR, meanT, out, out_size);

    // 2. per-class norms + diagonal distances (2 MB read)
    stat_kernel<<<NUM_CLASSES, 256, 0, stream>>>(meanR, meanT, stats);

    // 3. pair loss via norm-bound pruning (KBs read)
    pair_kernel<<<(NUM_CLASSES * NUM_CLASSES) / 256, 256, 0, stream>>>(
        meanR, meanT, stats, cnt, out);
}

// Round 4
// 101.219 us; speedup vs baseline: 2.0194x; 2.0194x over previous
//
#include <hip/hip_runtime.h>

#define N_SAMPLES 4096
#define DIM 2048
#define NUM_CLASSES 128
#define MARGIN 0.5f

// ---------------- ws layout (byte offsets) ----------------
// cnt   : C ints                        @ 0
// meanR : C*D floats                    @ 1024
// meanT : C*D floats                    @ 1024 + C*D*4
// stats : sqd[C] + cpref[32][C] floats  @ 1024 + 2*C*D*4
//
// History:
//   R3  = 118.8 us. R5 regression. R6 regression.
//   R8  = 115.4 us: loss 4-waves/tile.
//   R9  = 115.6 us: copy-free ping-pong mean — neutral (mean at BW floor).
//   R10 = 204.4 us REGRESSION: norm-difference prune useless (ra ⊥ cb, so
//         |ra|-|cb| ~ 0 for many pairs while true dist ~ 9.8) -> full-D
//         fallback taken everywhere (pair_kernel 113 us, FETCH 1.7 MB).
//         BUT: passed absmax 0.0 -> stat diag + fallback are bit-exact.
//   R11 (this): prefix-distance prune. sum_{k<32}(ra[k]-cb[k])^2 is an
//         exact lower bound on sq; E[prefix] ~ 1.5 >> 0.0625 = MARGIN^4,
//         P(fallback) ~ 1e-29. stat_kernel emits the center prefix
//         TRANSPOSED (cpref[32][C]) so pair_kernel b-loads coalesce.

// Kernel 1: per-class means, self-contained (no pre-sort).
// grid (2, C, 2), block 256. Each block scans targets (16 KB, L2-hot),
// compacts its class's rows into LDS, then streams its rows' float4
// columns with a copy-free ping-pong pipeline. Inputs read exactly once.
__global__ __launch_bounds__(256) void mean_kernel(
        const float* __restrict__ x1,
        const float* __restrict__ x2,
        const int* __restrict__ targets,
        int* __restrict__ cnt,
        float* __restrict__ meanR,
        float* __restrict__ meanT,
        float* __restrict__ d_out, int out_size) {
    __shared__ int s_rows[N_SAMPLES];
    __shared__ int s_n;
    const int tid = threadIdx.x;
    const int c = blockIdx.y;
    const float* __restrict__ x = (blockIdx.z == 0) ? x1 : x2;
    float* __restrict__ mean    = (blockIdx.z == 0) ? meanR : meanT;

    if (tid == 0) s_n = 0;
    if (blockIdx.x == 0 && blockIdx.y == 0 && blockIdx.z == 0) {
        for (int i = tid; i < out_size; i += 256) d_out[i] = 0.0f;  // pair runs after us
    }
    __syncthreads();

    // compact rows of class c (order irrelevant)
    const int4* __restrict__ t4 = (const int4*)targets;
    for (int i = tid; i < N_SAMPLES / 4; i += 256) {
        const int4 v = t4[i];
        const int base = i * 4;
        if (v.x == c) s_rows[atomicAdd(&s_n, 1)] = base;
        if (v.y == c) s_rows[atomicAdd(&s_n, 1)] = base + 1;
        if (v.z == c) s_rows[atomicAdd(&s_n, 1)] = base + 2;
        if (v.w == c) s_rows[atomicAdd(&s_n, 1)] = base + 3;
    }
    __syncthreads();
    const int n = s_n;

    const int col = blockIdx.x * 256 + tid;          // float4 index in [0,512)
    const float4* __restrict__ xs = (const float4*)x;
    float ax = 0.0f, ay = 0.0f, az = 0.0f, aw = 0.0f;

#define LOADG(B, g) do {                                               \
        const int _base = (g) * 8;                                     \
        _Pragma("unroll")                                              \
        for (int u = 0; u < 8; ++u) {                                  \
            const int _r = s_rows[_base + u];                          \
            B[u] = xs[(size_t)_r * (DIM / 4) + col];                   \
        }                                                              \
    } while (0)

#define ACCG(B) do {                                                   \
        _Pragma("unroll")                                              \
        for (int u = 0; u < 8; ++u) {                                  \
            ax += B[u].x; ay += B[u].y; az += B[u].z; aw += B[u].w;    \
        }                                                              \
    } while (0)

    const int nfull = n >> 3;        // full 8-row groups
    const int rem   = n & 7;         // 0..7 tail rows

    // Tail group: clamped indices, loads issued FIRST so their latency
    // hides under the whole body; masked accumulate at the very end.
    float4 T[8];
    if (rem) {
        const int tbase = nfull * 8;
#pragma unroll
        for (int u = 0; u < 8; ++u) {
            const int idx = tbase + ((u < rem) ? u : 0);  // clamp (uniform)
            T[u] = xs[(size_t)s_rows[idx] * (DIM / 4) + col];
        }
    }

    // Copy-free ping-pong body: acc(X) waits vmcnt(8) while the other
    // group's 8 loads remain in flight.
    if (nfull > 0) {
        float4 bufA[8], bufB[8];
        LOADG(bufA, 0);
        int g = 1;
        for (; g + 1 < nfull; g += 2) {
            LOADG(bufB, g);
            ACCG(bufA);
            LOADG(bufA, g + 1);
            ACCG(bufB);
        }
        if (g < nfull) {             // one loaded group + one pending
            LOADG(bufB, g);
            ACCG(bufA);
            ACCG(bufB);
        } else {
            ACCG(bufA);
        }
    }

    if (rem) {
#pragma unroll
        for (int u = 0; u < 8; ++u) {
            const float m = (u < rem) ? 1.0f : 0.0f;
            ax = fmaf(T[u].x, m, ax);
            ay = fmaf(T[u].y, m, ay);
            az = fmaf(T[u].z, m, az);
            aw = fmaf(T[u].w, m, aw);
        }
    }
#undef LOADG
#undef ACCG

    const float inv = 1.0f / (float)((n > 0) ? n : 1);
    float4 m; m.x = ax * inv; m.y = ay * inv; m.z = az * inv; m.w = aw * inv;
    ((float4*)mean)[(size_t)c * (DIM / 4) + col] = m;

    if (blockIdx.x == 0 && blockIdx.z == 0 && tid == 0) cnt[c] = n;
}

__device__ __forceinline__ float wave_sum64(float v) {
#pragma unroll
    for (int m = 32; m >= 1; m >>= 1) v += __shfl_xor(v, m, 64);
    return v;
}

// Kernel 2: per-class stats. One block per class (128 blocks).
// stats[c]                      = 0.25*|R[c]-T[c]|^2   (diag sq-dist, bit-
//                                 exact path verified in R10)
// stats[C + k*C + c], k<32      = 0.5*(R[c][k]+T[c][k]) (center prefix,
//                                 TRANSPOSED for coalesced pair loads)
__global__ __launch_bounds__(256) void stat_kernel(
        const float* __restrict__ meanR,
        const float* __restrict__ meanT,
        float* __restrict__ stats) {
    const int c = blockIdx.x;
    const int tid = threadIdx.x;
    const float4* __restrict__ r4 = (const float4*)(meanR + (size_t)c * DIM);
    const float4* __restrict__ t4 = (const float4*)(meanT + (size_t)c * DIM);
    float* __restrict__ cpref = stats + NUM_CLASSES;
    float sd = 0.0f;
    for (int i = tid; i < DIM / 4; i += 256) {   // 2 iterations
        const float4 r = r4[i], t = t4[i];
        if (i < 8) {                              // first 32 dims -> cpref
            cpref[(i * 4 + 0) * NUM_CLASSES + c] = 0.5f * (r.x + t.x);
            cpref[(i * 4 + 1) * NUM_CLASSES + c] = 0.5f * (r.y + t.y);
            cpref[(i * 4 + 2) * NUM_CLASSES + c] = 0.5f * (r.z + t.z);
            cpref[(i * 4 + 3) * NUM_CLASSES + c] = 0.5f * (r.w + t.w);
        }
        float dx;
        dx = r.x - t.x; sd = fmaf(dx, dx, sd);
        dx = r.y - t.y; sd = fmaf(dx, dx, sd);
        dx = r.z - t.z; sd = fmaf(dx, dx, sd);
        dx = r.w - t.w; sd = fmaf(dx, dx, sd);
    }
    sd = wave_sum64(sd);
    __shared__ float s[4];
    if ((tid & 63) == 0) s[tid >> 6] = sd;
    __syncthreads();
    if (tid == 0)
        stats[c] = 0.25f * ((s[0] + s[1]) + (s[2] + s[3]));
}

// Kernel 3: pair loss. 16384 pairs -> 64 blocks x 256 threads, one pair
// per thread. Off-diag margin term nonzero iff sq < MARGIN^4 = 0.0625;
// prune with the EXACT prefix bound sum_{k<32}(ra[k]-cb[k])^2 <= sq
// (E[prefix] ~ 1.5, P(fallback) ~ 1e-29). Fallback: full-D exact distance
// (bit-exact path verified in R10).
__global__ __launch_bounds__(256) void pair_kernel(
        const float* __restrict__ meanR,
        const float* __restrict__ meanT,
        const float* __restrict__ stats,
        const int* __restrict__ cnt,
        float* __restrict__ d_out) {
    const int idx = blockIdx.x * 256 + threadIdx.x;   // 0..16383
    const int a = idx >> 7;          // wave-uniform (broadcast loads)
    const int b = idx & 127;         // coalesced
    const float* __restrict__ sqd   = stats;
    const float* __restrict__ cpref = stats + NUM_CLASSES;

    const float invN2 = 1.0f / ((float)N_SAMPLES * (float)N_SAMPLES);
    const float w = (float)cnt[a] * (float)cnt[b] * invN2;

    float total;
    if (a == b) {
        const float t = fmaxf(sqd[a], 1e-12f);   // d^2 for BOTH modalities
        total = w * (t + t);
    } else {
        const float THR = MARGIN * MARGIN * MARGIN * MARGIN;  // 0.0625
        float s1 = 0.0f, s2 = 0.0f;
        const float4* __restrict__ ra4 = (const float4*)(meanR + (size_t)a * DIM);
        const float4* __restrict__ ta4 = (const float4*)(meanT + (size_t)a * DIM);
#pragma unroll
        for (int k4 = 0; k4 < 8; ++k4) {
            const float4 rv = ra4[k4];           // wave-uniform -> broadcast
            const float4 tv = ta4[k4];
            const float c0 = cpref[(k4 * 4 + 0) * NUM_CLASSES + b];  // coalesced
            const float c1 = cpref[(k4 * 4 + 1) * NUM_CLASSES + b];
            const float c2 = cpref[(k4 * 4 + 2) * NUM_CLASSES + b];
            const float c3 = cpref[(k4 * 4 + 3) * NUM_CLASSES + b];
            float d;
            d = rv.x - c0; s1 = fmaf(d, d, s1);
            d = rv.y - c1; s1 = fmaf(d, d, s1);
            d = rv.z - c2; s1 = fmaf(d, d, s1);
            d = rv.w - c3; s1 = fmaf(d, d, s1);
            d = tv.x - c0; s2 = fmaf(d, d, s2);
            d = tv.y - c1; s2 = fmaf(d, d, s2);
            d = tv.z - c2; s2 = fmaf(d, d, s2);
            d = tv.w - c3; s2 = fmaf(d, d, s2);
        }
        float t1 = 0.0f, t2 = 0.0f;
        if ((s1 < THR) | (s2 < THR)) {
            // exact squared distances (correctness fallback; unreachable
            // unless prefix sum < MARGIN^4 — P ~ 1e-29 on gaussian data)
            float sq1 = 0.0f, sq2 = 0.0f;
            const float* __restrict__ ra = meanR + (size_t)a * DIM;
            const float* __restrict__ ta = meanT + (size_t)a * DIM;
            const float* __restrict__ rb = meanR + (size_t)b * DIM;
            const float* __restrict__ tb = meanT + (size_t)b * DIM;
            for (int k = 0; k < DIM; ++k) {
                const float cb = 0.5f * (rb[k] + tb[k]);
                const float e1 = ra[k] - cb;
                const float e2 = ta[k] - cb;
                sq1 = fmaf(e1, e1, sq1);
                sq2 = fmaf(e2, e2, sq2);
            }
            sq1 = fmaxf(sq1, 1e-12f);
            sq2 = fmaxf(sq2, 1e-12f);
            const float dd1 = sqrtf(sqrtf(sq1) + 1e-10f);
            const float dd2 = sqrtf(sqrtf(sq2) + 1e-10f);
            const float r1 = fmaxf(MARGIN - dd1, 0.0f);
            const float r2 = fmaxf(MARGIN - dd2, 0.0f);
            t1 = r1 * r1;
            t2 = r2 * r2;
        }
        total = w * (t1 + t2);
    }

    total = wave_sum64(total);
    __shared__ float sp[4];
    if ((threadIdx.x & 63) == 0) sp[threadIdx.x >> 6] = total;
    __syncthreads();
    if (threadIdx.x == 0)
        atomicAdd(d_out, (sp[0] + sp[1]) + (sp[2] + sp[3]));
}

extern "C" void kernel_launch(void* const* d_in, const int* in_sizes, int n_in,
                              void* d_out, int out_size, void* d_ws, size_t ws_size,
                              hipStream_t stream) {
    const float* modal1 = (const float*)d_in[0];
    const float* modal2 = (const float*)d_in[1];
    const int* targets  = (const int*)d_in[2];
    float* out = (float*)d_out;

    char* ws = (char*)d_ws;
    int*   cnt   = (int*)(ws + 0);
    float* meanR = (float*)(ws + 1024);
    float* meanT = (float*)(ws + 1024 + (size_t)NUM_CLASSES * DIM * 4);
    float* stats = (float*)(ws + 1024 + 2 * (size_t)NUM_CLASSES * DIM * 4);

    // 1. per-class means (self-gathering; also zeroes d_out, publishes cnt)
    dim3 gridB(2, NUM_CLASSES, 2);
    mean_kernel<<<gridB, 256, 0, stream>>>(modal1, modal2, targets, cnt,
                                           meanR, meanT, out, out_size);

    // 2. diagonal distances + transposed 32-dim center prefix (2 MB read)
    stat_kernel<<<NUM_CLASSES, 256, 0, stream>>>(meanR, meanT, stats);

    // 3. pair loss via exact prefix-distance pruning (KBs read)
    pair_kernel<<<(NUM_CLASSES * NUM_CLASSES) / 256, 256, 0, stream>>>(
        meanR, meanT, stats, cnt, out);
}

// Round 5
// 97.632 us; speedup vs baseline: 2.0936x; 1.0367x over previous
//
#include <hip/hip_runtime.h>

#define N_SAMPLES 4096
#define DIM 2048
#define NUM_CLASSES 128
#define MARGIN 0.5f

// ---------------- ws layout (byte offsets) ----------------
// cnt      : C ints                      @ 0
// meanR    : C*D floats                  @ 1024
// meanT    : C*D floats                  @ 1024 + C*D*4
// stats    : sqd_part[2][C] + cpref[32][C] floats  @ 1024 + 2*C*D*4
//
// History:
//   R3  = 118.8. R5/R6 regressions. R8 = 115.4 (loss 4-waves/tile).
//   R9  = 115.6: ping-pong mean — neutral (mean at BW floor).
//   R10 = 204.4 REGRESSION: norm-diff prune uninformative -> full-D
//         fallback everywhere. (But verified diag + fallback bit-exact.)
//   R11 = 101.2: prefix-distance prune (exact lower bound, E~1.5 >>
//         0.0625) -> pair_kernel ~1 us. Matched prediction.
//   R12 (this): fuse stat into mean. Grid (2, C) x 512 thr: waves 0-3 =
//         modal1 slice, waves 4-7 = modal2 slice in the SAME block ->
//         block computes partial 0.25|R-T|^2 (T via 4 KB LDS) into
//         sqd_part[half][c] (plain stores, 2 fixed-order contributors,
//         deterministic) and block (0,c) writes cpref[32][C] directly.
//         stat_kernel + its launch gap + 2 MB re-read eliminated; target
//         scans halved. 2 dispatches total.

// Kernel 1: per-class means + fused stats.
__global__ __launch_bounds__(512) void mean_kernel(
        const float* __restrict__ x1,
        const float* __restrict__ x2,
        const int* __restrict__ targets,
        int* __restrict__ cnt,
        float* __restrict__ meanR,
        float* __restrict__ meanT,
        float* __restrict__ stats,
        float* __restrict__ d_out, int out_size) {
    __shared__ int s_rows[N_SAMPLES];
    __shared__ int s_n;
    __shared__ float4 s_T[256];      // modal-2 mean slice for sqd/cpref
    __shared__ float s_p[4];
    const int tid = threadIdx.x;
    const int half = tid >> 8;       // 0: modal1/R, 1: modal2/T
    const int lane256 = tid & 255;
    const int c = blockIdx.y;
    const int bx = blockIdx.x;       // column half
    const float* __restrict__ x = half ? x2 : x1;
    float* __restrict__ mean    = half ? meanT : meanR;

    if (tid == 0) s_n = 0;
    if (bx == 0 && c == 0) {
        for (int i = tid; i < out_size; i += 512) d_out[i] = 0.0f;  // pair runs after us
    }
    __syncthreads();

    // compact rows of class c (order irrelevant) — ONE scan per block
    const int4* __restrict__ t4 = (const int4*)targets;
    for (int i = tid; i < N_SAMPLES / 4; i += 512) {   // 2 iterations
        const int4 v = t4[i];
        const int base = i * 4;
        if (v.x == c) s_rows[atomicAdd(&s_n, 1)] = base;
        if (v.y == c) s_rows[atomicAdd(&s_n, 1)] = base + 1;
        if (v.z == c) s_rows[atomicAdd(&s_n, 1)] = base + 2;
        if (v.w == c) s_rows[atomicAdd(&s_n, 1)] = base + 3;
    }
    __syncthreads();
    const int n = s_n;

    const int col = bx * 256 + lane256;              // float4 index in [0,512)
    const float4* __restrict__ xs = (const float4*)x;
    float ax = 0.0f, ay = 0.0f, az = 0.0f, aw = 0.0f;

#define LOADG(B, g) do {                                               \
        const int _base = (g) * 8;                                     \
        _Pragma("unroll")                                              \
        for (int u = 0; u < 8; ++u) {                                  \
            const int _r = s_rows[_base + u];                          \
            B[u] = xs[(size_t)_r * (DIM / 4) + col];                   \
        }                                                              \
    } while (0)

#define ACCG(B) do {                                                   \
        _Pragma("unroll")                                              \
        for (int u = 0; u < 8; ++u) {                                  \
            ax += B[u].x; ay += B[u].y; az += B[u].z; aw += B[u].w;    \
        }                                                              \
    } while (0)

    const int nfull = n >> 3;        // full 8-row groups
    const int rem   = n & 7;         // 0..7 tail rows

    // Tail group: clamped indices, loads issued FIRST (hidden under body)
    float4 T[8];
    if (rem) {
        const int tbase = nfull * 8;
#pragma unroll
        for (int u = 0; u < 8; ++u) {
            const int idx = tbase + ((u < rem) ? u : 0);  // clamp (uniform)
            T[u] = xs[(size_t)s_rows[idx] * (DIM / 4) + col];
        }
    }

    // Copy-free ping-pong body: 8 loads always in flight.
    if (nfull > 0) {
        float4 bufA[8], bufB[8];
        LOADG(bufA, 0);
        int g = 1;
        for (; g + 1 < nfull; g += 2) {
            LOADG(bufB, g);
            ACCG(bufA);
            LOADG(bufA, g + 1);
            ACCG(bufB);
        }
        if (g < nfull) {
            LOADG(bufB, g);
            ACCG(bufA);
            ACCG(bufB);
        } else {
            ACCG(bufA);
        }
    }

    if (rem) {
#pragma unroll
        for (int u = 0; u < 8; ++u) {
            const float m = (u < rem) ? 1.0f : 0.0f;
            ax = fmaf(T[u].x, m, ax);
            ay = fmaf(T[u].y, m, ay);
            az = fmaf(T[u].z, m, az);
            aw = fmaf(T[u].w, m, aw);
        }
    }
#undef LOADG
#undef ACCG

    const float inv = 1.0f / (float)((n > 0) ? n : 1);
    float4 m; m.x = ax * inv; m.y = ay * inv; m.z = az * inv; m.w = aw * inv;
    ((float4*)mean)[(size_t)c * (DIM / 4) + col] = m;

    // ---- fused stats: T half publishes slice, R half diffs it ----
    if (half) s_T[lane256] = m;
    __syncthreads();

    if (!half) {
        const float4 t = s_T[lane256];
        float part = 0.0f, d;
        d = m.x - t.x; part = fmaf(d, d, part);
        d = m.y - t.y; part = fmaf(d, d, part);
        d = m.z - t.z; part = fmaf(d, d, part);
        d = m.w - t.w; part = fmaf(d, d, part);
#pragma unroll
        for (int s = 32; s >= 1; s >>= 1) part += __shfl_xor(part, s, 64);
        if ((tid & 63) == 0) s_p[tid >> 6] = part;
    }
    __syncthreads();
    if (tid == 0) {
        stats[bx * NUM_CLASSES + c] =
            0.25f * ((s_p[0] + s_p[1]) + (s_p[2] + s_p[3]));
        if (bx == 0) cnt[c] = n;
    }

    // cpref[32][C] (transposed): dims 0..31 live in bx==0, threads 0..7 (R half)
    if (bx == 0 && tid < 8) {
        float* __restrict__ cpref = stats + 2 * NUM_CLASSES;
        const float4 t = s_T[tid];           // T mean, cols 4*tid..4*tid+3
        cpref[(4 * tid + 0) * NUM_CLASSES + c] = 0.5f * (m.x + t.x);
        cpref[(4 * tid + 1) * NUM_CLASSES + c] = 0.5f * (m.y + t.y);
        cpref[(4 * tid + 2) * NUM_CLASSES + c] = 0.5f * (m.z + t.z);
        cpref[(4 * tid + 3) * NUM_CLASSES + c] = 0.5f * (m.w + t.w);
    }
}

__device__ __forceinline__ float wave_sum64(float v) {
#pragma unroll
    for (int m = 32; m >= 1; m >>= 1) v += __shfl_xor(v, m, 64);
    return v;
}

// Kernel 2: pair loss. 16384 pairs -> 64 blocks x 256 threads, one pair
// per thread. Off-diag margin term nonzero iff sq < MARGIN^4 = 0.0625;
// prune with the EXACT prefix bound sum_{k<32}(ra[k]-cb[k])^2 <= sq.
// Fallback: full-D exact distance (bit-exact path verified in R10).
__global__ __launch_bounds__(256) void pair_kernel(
        const float* __restrict__ meanR,
        const float* __restrict__ meanT,
        const float* __restrict__ stats,
        const int* __restrict__ cnt,
        float* __restrict__ d_out) {
    const int idx = blockIdx.x * 256 + threadIdx.x;   // 0..16383
    const int a = idx >> 7;          // wave-uniform (broadcast loads)
    const int b = idx & 127;         // coalesced
    const float* __restrict__ sqdp  = stats;                 // [2][C]
    const float* __restrict__ cpref = stats + 2 * NUM_CLASSES;

    const float invN2 = 1.0f / ((float)N_SAMPLES * (float)N_SAMPLES);
    const float w = (float)cnt[a] * (float)cnt[b] * invN2;

    float total;
    if (a == b) {
        const float sq = sqdp[a] + sqdp[NUM_CLASSES + a];  // fixed order
        const float t = fmaxf(sq, 1e-12f);   // d^2 for BOTH modalities
        total = w * (t + t);
    } else {
        const float THR = MARGIN * MARGIN * MARGIN * MARGIN;  // 0.0625
        float s1 = 0.0f, s2 = 0.0f;
        const float4* __restrict__ ra4 = (const float4*)(meanR + (size_t)a * DIM);
        const float4* __restrict__ ta4 = (const float4*)(meanT + (size_t)a * DIM);
#pragma unroll
        for (int k4 = 0; k4 < 8; ++k4) {
            const float4 rv = ra4[k4];           // wave-uniform -> broadcast
            const float4 tv = ta4[k4];
            const float c0 = cpref[(k4 * 4 + 0) * NUM_CLASSES + b];  // coalesced
            const float c1 = cpref[(k4 * 4 + 1) * NUM_CLASSES + b];
            const float c2 = cpref[(k4 * 4 + 2) * NUM_CLASSES + b];
            const float c3 = cpref[(k4 * 4 + 3) * NUM_CLASSES + b];
            float d;
            d = rv.x - c0; s1 = fmaf(d, d, s1);
            d = rv.y - c1; s1 = fmaf(d, d, s1);
            d = rv.z - c2; s1 = fmaf(d, d, s1);
            d = rv.w - c3; s1 = fmaf(d, d, s1);
            d = tv.x - c0; s2 = fmaf(d, d, s2);
            d = tv.y - c1; s2 = fmaf(d, d, s2);
            d = tv.z - c2; s2 = fmaf(d, d, s2);
            d = tv.w - c3; s2 = fmaf(d, d, s2);
        }
        float t1 = 0.0f, t2 = 0.0f;
        if ((s1 < THR) | (s2 < THR)) {
            // exact squared distances (correctness fallback; unreachable
            // unless prefix sum < MARGIN^4 — P ~ 1e-29 on gaussian data)
            float sq1 = 0.0f, sq2 = 0.0f;
            const float* __restrict__ ra = meanR + (size_t)a * DIM;
            const float* __restrict__ ta = meanT + (size_t)a * DIM;
            const float* __restrict__ rb = meanR + (size_t)b * DIM;
            const float* __restrict__ tb = meanT + (size_t)b * DIM;
            for (int k = 0; k < DIM; ++k) {
                const float cb = 0.5f * (rb[k] + tb[k]);
                const float e1 = ra[k] - cb;
                const float e2 = ta[k] - cb;
                sq1 = fmaf(e1, e1, sq1);
                sq2 = fmaf(e2, e2, sq2);
            }
            sq1 = fmaxf(sq1, 1e-12f);
            sq2 = fmaxf(sq2, 1e-12f);
            const float dd1 = sqrtf(sqrtf(sq1) + 1e-10f);
            const float dd2 = sqrtf(sqrtf(sq2) + 1e-10f);
            const float r1 = fmaxf(MARGIN - dd1, 0.0f);
            const float r2 = fmaxf(MARGIN - dd2, 0.0f);
            t1 = r1 * r1;
            t2 = r2 * r2;
        }
        total = w * (t1 + t2);
    }

    total = wave_sum64(total);
    __shared__ float sp[4];
    if ((threadIdx.x & 63) == 0) sp[threadIdx.x >> 6] = total;
    __syncthreads();
    if (threadIdx.x == 0)
        atomicAdd(d_out, (sp[0] + sp[1]) + (sp[2] + sp[3]));
}

extern "C" void kernel_launch(void* const* d_in, const int* in_sizes, int n_in,
                              void* d_out, int out_size, void* d_ws, size_t ws_size,
                              hipStream_t stream) {
    const float* modal1 = (const float*)d_in[0];
    const float* modal2 = (const float*)d_in[1];
    const int* targets  = (const int*)d_in[2];
    float* out = (float*)d_out;

    char* ws = (char*)d_ws;
    int*   cnt   = (int*)(ws + 0);
    float* meanR = (float*)(ws + 1024);
    float* meanT = (float*)(ws + 1024 + (size_t)NUM_CLASSES * DIM * 4);
    float* stats = (float*)(ws + 1024 + 2 * (size_t)NUM_CLASSES * DIM * 4);

    // 1. per-class means + fused stats (also zeroes d_out, publishes cnt)
    dim3 gridB(2, NUM_CLASSES);
    mean_kernel<<<gridB, 512, 0, stream>>>(modal1, modal2, targets, cnt,
                                           meanR, meanT, stats, out, out_size);

    // 2. pair loss via exact prefix-distance pruning (KBs read)
    pair_kernel<<<(NUM_CLASSES * NUM_CLASSES) / 256, 256, 0, stream>>>(
        meanR, meanT, stats, cnt, out);
}